// Round 1
// baseline (17508.154 us; speedup 1.0000x reference)
//
#include <hip/hip_runtime.h>
#include <math.h>

// Problem constants (fixed by the reference)
#define DM 1024      // model dim
#define SEQ 2048     // sequence length
#define BATCH 2
#define NHEAD 16
#define HDIM 64      // head dim
#define NLAYER 8
#define FFDIM 4096   // FFN hidden
#define MROWS (BATCH*SEQ)   // 4096 total rows

// ---------------------------------------------------------------------------
// softplus matching jax.nn.softplus = log1p(exp(x)) (stable form)
__device__ __forceinline__ float softplus_f(float x){
    return fmaxf(x, 0.0f) + log1pf(__expf(-fabsf(x)));
}

// ---------------------------------------------------------------------------
// LayerNorm: one block per row of 1024 floats. eps = 1e-3 (keras default).
__global__ __launch_bounds__(256) void ln_kernel(
    const float* __restrict__ x, const float* __restrict__ gamma,
    const float* __restrict__ beta, float* __restrict__ out)
{
    const int row = blockIdx.x;
    const int t = threadIdx.x;
    const float4 v = ((const float4*)(x + (size_t)row * DM))[t];
    float s  = v.x + v.y + v.z + v.w;
    float s2 = v.x*v.x + v.y*v.y + v.z*v.z + v.w*v.w;
    #pragma unroll
    for (int off = 32; off > 0; off >>= 1){
        s  += __shfl_down(s,  off);
        s2 += __shfl_down(s2, off);
    }
    __shared__ float red[8];
    const int wid = t >> 6;
    if ((t & 63) == 0){ red[wid] = s; red[4 + wid] = s2; }
    __syncthreads();
    if (t == 0){
        red[0] = red[0] + red[1] + red[2] + red[3];
        red[4] = red[4] + red[5] + red[6] + red[7];
    }
    __syncthreads();
    const float mean = red[0] * (1.0f / DM);
    const float var  = red[4] * (1.0f / DM) - mean * mean;
    const float rstd = rsqrtf(var + 1e-3f);
    const float4 g  = ((const float4*)gamma)[t];
    const float4 bt = ((const float4*)beta)[t];
    float4 o;
    o.x = (v.x - mean) * rstd * g.x + bt.x;
    o.y = (v.y - mean) * rstd * g.y + bt.y;
    o.z = (v.z - mean) * rstd * g.z + bt.z;
    o.w = (v.w - mean) * rstd * g.w + bt.w;
    ((float4*)(out + (size_t)row * DM))[t] = o;
}

// ---------------------------------------------------------------------------
// fp32 GEMM: C[M,N] = A[M,K] @ W[K,N] + bias[N]  (+ optional softplus,
// + optional residual add). 128x128 block tile, BK=16, 256 threads,
// 8x8 micro-tile per thread. All dims divide tiles evenly here.
template<bool SOFTPLUS, bool RESIDUAL>
__global__ __launch_bounds__(256) void gemm_kernel(
    const float* __restrict__ A, const float* __restrict__ W,
    const float* __restrict__ bias, const float* __restrict__ resid,
    float* __restrict__ C, int N, int K)
{
    __shared__ float As[16][132];   // [k][m], padded
    __shared__ float Bs[16][132];   // [k][n], padded
    const int t  = threadIdx.x;
    const int bm = blockIdx.y * 128;
    const int bn = blockIdx.x * 128;
    const int tx = t & 15, ty = t >> 4;
    // A staging: thread loads rows (t>>2) and (t>>2)+64, float4 at col (t&3)*4
    const int a_row = t >> 2;
    const int a_c4  = (t & 3) * 4;
    // W staging: thread loads rows (t>>5) and (t>>5)+8, float4 at col (t&31)*4
    const int b_row = t >> 5;
    const int b_c   = (t & 31) * 4;

    float acc[8][8] = {};

    for (int k0 = 0; k0 < K; k0 += 16){
        const float4 a0 = *(const float4*)(A + (size_t)(bm + a_row     ) * K + k0 + a_c4);
        const float4 a1 = *(const float4*)(A + (size_t)(bm + a_row + 64) * K + k0 + a_c4);
        const float4 w0 = *(const float4*)(W + (size_t)(k0 + b_row    ) * N + bn + b_c);
        const float4 w1 = *(const float4*)(W + (size_t)(k0 + b_row + 8) * N + bn + b_c);
        __syncthreads();
        As[a_c4+0][a_row] = a0.x; As[a_c4+1][a_row] = a0.y;
        As[a_c4+2][a_row] = a0.z; As[a_c4+3][a_row] = a0.w;
        As[a_c4+0][a_row+64] = a1.x; As[a_c4+1][a_row+64] = a1.y;
        As[a_c4+2][a_row+64] = a1.z; As[a_c4+3][a_row+64] = a1.w;
        *(float4*)&Bs[b_row  ][b_c] = w0;
        *(float4*)&Bs[b_row+8][b_c] = w1;
        __syncthreads();
        #pragma unroll
        for (int k = 0; k < 16; k++){
            float a[8], b[8];
            *(float4*)&a[0] = *(const float4*)&As[k][ty*8];
            *(float4*)&a[4] = *(const float4*)&As[k][ty*8+4];
            *(float4*)&b[0] = *(const float4*)&Bs[k][tx*8];
            *(float4*)&b[4] = *(const float4*)&Bs[k][tx*8+4];
            #pragma unroll
            for (int i = 0; i < 8; i++)
                #pragma unroll
                for (int j = 0; j < 8; j++)
                    acc[i][j] = fmaf(a[i], b[j], acc[i][j]);
        }
    }

    const float4* bias4 = (const float4*)bias;
    #pragma unroll
    for (int i = 0; i < 8; i++){
        const size_t row = (size_t)bm + ty*8 + i;
        #pragma unroll
        for (int j4 = 0; j4 < 2; j4++){
            const int col = bn + tx*8 + j4*4;
            const float4 bb = bias4[col >> 2];
            float4 r;
            r.x = acc[i][j4*4+0] + bb.x;
            r.y = acc[i][j4*4+1] + bb.y;
            r.z = acc[i][j4*4+2] + bb.z;
            r.w = acc[i][j4*4+3] + bb.w;
            if (SOFTPLUS){
                r.x = softplus_f(r.x); r.y = softplus_f(r.y);
                r.z = softplus_f(r.z); r.w = softplus_f(r.w);
            }
            if (RESIDUAL){
                const float4 rv = *(const float4*)(resid + row * N + col);
                r.x += rv.x; r.y += rv.y; r.z += rv.z; r.w += rv.w;
            }
            *(float4*)(C + row * N + col) = r;
        }
    }
}

// ---------------------------------------------------------------------------
// Flash attention (fp32, online softmax), ALiBi + causal.
// Grid: (SEQ/64, NHEAD, BATCH); 256 threads.
// Thread (ty=t/16, tx=t%15+1...): ty picks 4 q-rows, tx picks 4 k-cols
// (score phase) / 4 d-cols (PV phase). Per-row m/l replicated over the 16
// tx lanes; reductions via __shfl_xor over lane bits 0..3 (in-wave).
__global__ __launch_bounds__(256, 2) void attn_kernel(
    const float* __restrict__ qg,   // [B,S,D] with head h at cols h*64..
    const float* __restrict__ kvg,  // [B,S,2D]: K at cols 0..D, V at D..2D
    float* __restrict__ outg)       // [B,S,D]
{
    __shared__ float Qs[64][68];
    __shared__ float Ks[64][68];
    __shared__ float Vs[64][68];
    __shared__ float Ps[64][68];

    const int b = blockIdx.z, h = blockIdx.y, qt = blockIdx.x;
    const int t  = threadIdx.x;
    const int tx = t & 15, ty = t >> 4;
    const int lr = t >> 2, lc = t & 3;   // staging: row lr, float4 group lc

    const size_t qrow0 = (size_t)(b * SEQ + qt * 64);
    #pragma unroll
    for (int j = 0; j < 4; j++){
        const int d4 = lc + j*4;
        *(float4*)&Qs[lr][d4*4] =
            *(const float4*)(qg + (qrow0 + lr) * DM + h*HDIM + d4*4);
    }

    const float mh = exp2f(-0.5f * (float)(h + 1));   // ALiBi slope 2^{-(h+1)/2}
    float m_i[4], l_i[4], accO[4][4];
    #pragma unroll
    for (int i = 0; i < 4; i++){
        m_i[i] = -1e30f; l_i[i] = 0.0f;
        accO[i][0] = accO[i][1] = accO[i][2] = accO[i][3] = 0.0f;
    }

    for (int kt = 0; kt <= qt; kt++){
        __syncthreads();   // prior PV done before Ks/Vs/Ps overwritten (covers Qs at kt=0)
        const size_t krow0 = (size_t)(b * SEQ + kt * 64);
        #pragma unroll
        for (int j = 0; j < 4; j++){
            const int d4 = lc + j*4;
            *(float4*)&Ks[lr][d4*4] =
                *(const float4*)(kvg + (krow0 + lr) * (2*DM) + h*HDIM + d4*4);
            *(float4*)&Vs[lr][d4*4] =
                *(const float4*)(kvg + (krow0 + lr) * (2*DM) + DM + h*HDIM + d4*4);
        }
        __syncthreads();

        // --- QK^T: 4x4 scores per thread ---
        float sc[4][4] = {};
        #pragma unroll 4
        for (int d4 = 0; d4 < 16; d4++){
            float4 qv[4], kk[4];
            #pragma unroll
            for (int i = 0; i < 4; i++) qv[i] = *(const float4*)&Qs[ty*4+i][d4*4];
            #pragma unroll
            for (int j = 0; j < 4; j++) kk[j] = *(const float4*)&Ks[tx*4+j][d4*4];
            #pragma unroll
            for (int i = 0; i < 4; i++)
                #pragma unroll
                for (int j = 0; j < 4; j++)
                    sc[i][j] += qv[i].x*kk[j].x + qv[i].y*kk[j].y
                              + qv[i].z*kk[j].z + qv[i].w*kk[j].w;
        }

        // --- scale + ALiBi + causal mask ---
        const int q0 = qt*64 + ty*4, k0 = kt*64 + tx*4;
        #pragma unroll
        for (int i = 0; i < 4; i++)
            #pragma unroll
            for (int j = 0; j < 4; j++){
                const int qi = q0 + i, kj = k0 + j;
                sc[i][j] = (kj <= qi) ? fmaf(sc[i][j], 0.125f, mh * (float)(kj - qi))
                                      : -1e30f;
            }

        // --- online softmax: row max/sum across j and the 16 tx lanes ---
        float rmax[4], alpha[4], rsum[4];
        #pragma unroll
        for (int i = 0; i < 4; i++)
            rmax[i] = fmaxf(fmaxf(sc[i][0], sc[i][1]), fmaxf(sc[i][2], sc[i][3]));
        #pragma unroll
        for (int off = 1; off < 16; off <<= 1)
            #pragma unroll
            for (int i = 0; i < 4; i++)
                rmax[i] = fmaxf(rmax[i], __shfl_xor(rmax[i], off));
        #pragma unroll
        for (int i = 0; i < 4; i++){
            const float nm = fmaxf(m_i[i], rmax[i]);
            alpha[i] = __expf(m_i[i] - nm);
            m_i[i] = nm;
        }
        #pragma unroll
        for (int i = 0; i < 4; i++){
            float su = 0.0f;
            #pragma unroll
            for (int j = 0; j < 4; j++){
                const float p = __expf(sc[i][j] - m_i[i]);
                sc[i][j] = p; su += p;
            }
            rsum[i] = su;
        }
        #pragma unroll
        for (int off = 1; off < 16; off <<= 1)
            #pragma unroll
            for (int i = 0; i < 4; i++)
                rsum[i] += __shfl_xor(rsum[i], off);
        #pragma unroll
        for (int i = 0; i < 4; i++) l_i[i] = l_i[i] * alpha[i] + rsum[i];

        // --- exchange P through LDS ---
        #pragma unroll
        for (int i = 0; i < 4; i++)
            *(float4*)&Ps[ty*4+i][tx*4] =
                make_float4(sc[i][0], sc[i][1], sc[i][2], sc[i][3]);
        __syncthreads();

        // --- PV: O[4 rows][4 d-cols], d-cols tx*4.. ---
        #pragma unroll
        for (int i = 0; i < 4; i++){
            accO[i][0] *= alpha[i]; accO[i][1] *= alpha[i];
            accO[i][2] *= alpha[i]; accO[i][3] *= alpha[i];
        }
        #pragma unroll 4
        for (int k4 = 0; k4 < 16; k4++){
            float4 pv[4], vv[4];
            #pragma unroll
            for (int i = 0; i < 4; i++) pv[i] = *(const float4*)&Ps[ty*4+i][k4*4];
            #pragma unroll
            for (int j = 0; j < 4; j++) vv[j] = *(const float4*)&Vs[k4*4+j][tx*4];
            #pragma unroll
            for (int i = 0; i < 4; i++){
                const float4 p = pv[i];
                accO[i][0] += p.x*vv[0].x + p.y*vv[1].x + p.z*vv[2].x + p.w*vv[3].x;
                accO[i][1] += p.x*vv[0].y + p.y*vv[1].y + p.z*vv[2].y + p.w*vv[3].y;
                accO[i][2] += p.x*vv[0].z + p.y*vv[1].z + p.z*vv[2].z + p.w*vv[3].z;
                accO[i][3] += p.x*vv[0].w + p.y*vv[1].w + p.z*vv[2].w + p.w*vv[3].w;
            }
        }
    }

    #pragma unroll
    for (int i = 0; i < 4; i++){
        const float inv = 1.0f / l_i[i];
        float4 o;
        o.x = accO[i][0] * inv; o.y = accO[i][1] * inv;
        o.z = accO[i][2] * inv; o.w = accO[i][3] * inv;
        *(float4*)(outg + (qrow0 + ty*4 + i) * DM + h*HDIM + tx*4) = o;
    }
}

// ---------------------------------------------------------------------------
extern "C" void kernel_launch(void* const* d_in, const int* in_sizes, int n_in,
                              void* d_out, int out_size, void* d_ws, size_t ws_size,
                              hipStream_t stream)
{
    (void)in_sizes; (void)n_in; (void)out_size; (void)ws_size;

    const float* x_in = (const float*)d_in[0];
    const float* fg   = (const float*)d_in[1];
    const float* fb   = (const float*)d_in[2];
    const float* wq   = (const float*)d_in[3];
    const float* bq   = (const float*)d_in[4];
    const float* wkv  = (const float*)d_in[5];
    const float* bkv  = (const float*)d_in[6];
    const float* wo   = (const float*)d_in[7];
    const float* bo   = (const float*)d_in[8];
    const float* w1   = (const float*)d_in[9];
    const float* b1   = (const float*)d_in[10];
    const float* w2   = (const float*)d_in[11];
    const float* b2   = (const float*)d_in[12];
    const float* attg = (const float*)d_in[13];
    const float* attb = (const float*)d_in[14];
    const float* ffng = (const float*)d_in[15];
    const float* ffnb = (const float*)d_in[16];

    float* x = (float*)d_out;                 // residual stream lives in d_out
    float* ws = (float*)d_ws;
    const size_t NR = (size_t)MROWS;          // 4096
    float* hbuf   = ws;                       // 4M floats
    float* qbuf   = ws + NR*DM;               // 4M
    float* kvbuf  = ws + 2*NR*DM;             // 8M
    float* attbuf = ws + 4*NR*DM;             // 4M
    float* h1buf  = ws + 5*NR*DM;             // 16M  (total 36M floats = 144 MB)

    hipMemcpyAsync(x, x_in, NR*DM*sizeof(float), hipMemcpyDeviceToDevice, stream);

    const dim3 blk(256);
    const dim3 g_sq (DM/128,    MROWS/128);   // (8,32)  N=1024
    const dim3 g_kv (2*DM/128,  MROWS/128);   // (16,32) N=2048
    const dim3 g_ff (FFDIM/128, MROWS/128);   // (32,32) N=4096
    const dim3 g_at (SEQ/64, NHEAD, BATCH);   // (32,16,2)

    for (int i = 0; i < NLAYER; i++){
        const float* wq_i  = wq  + (size_t)i*DM*DM;
        const float* bq_i  = bq  + (size_t)i*DM;
        const float* wkv_i = wkv + (size_t)i*DM*2*DM;
        const float* bkv_i = bkv + (size_t)i*2*DM;
        const float* wo_i  = wo  + (size_t)i*DM*DM;
        const float* bo_i  = bo  + (size_t)i*DM;
        const float* w1_i  = w1  + (size_t)i*DM*FFDIM;
        const float* b1_i  = b1  + (size_t)i*FFDIM;
        const float* w2_i  = w2  + (size_t)i*FFDIM*DM;
        const float* b2_i  = b2  + (size_t)i*DM;

        // h = LN(x)
        ln_kernel<<<MROWS, blk, 0, stream>>>(x, attg + (size_t)i*DM, attb + (size_t)i*DM, hbuf);
        // q = h @ wq + bq ; kv = h @ wkv + bkv
        gemm_kernel<false,false><<<g_sq, blk, 0, stream>>>(hbuf, wq_i,  bq_i,  nullptr, qbuf,  DM,   DM);
        gemm_kernel<false,false><<<g_kv, blk, 0, stream>>>(hbuf, wkv_i, bkv_i, nullptr, kvbuf, 2*DM, DM);
        // att = flash_attention(q, kv)
        attn_kernel<<<g_at, blk, 0, stream>>>(qbuf, kvbuf, attbuf);
        // x = x + att @ wo + bo
        gemm_kernel<false,true><<<g_sq, blk, 0, stream>>>(attbuf, wo_i, bo_i, x, x, DM, DM);
        // h = LN(x)
        ln_kernel<<<MROWS, blk, 0, stream>>>(x, ffng + (size_t)i*DM, ffnb + (size_t)i*DM, hbuf);
        // h1 = softplus(h @ w1 + b1)
        gemm_kernel<true,false><<<g_ff, blk, 0, stream>>>(hbuf, w1_i, b1_i, nullptr, h1buf, FFDIM, DM);
        // x = x + h1 @ w2 + b2
        gemm_kernel<false,true><<<g_sq, blk, 0, stream>>>(h1buf, w2_i, b2_i, x, x, DM, FFDIM);
    }
    // out = LN(x)  (in-place on d_out; per-thread read-before-write is safe)
    ln_kernel<<<MROWS, blk, 0, stream>>>(x, fg, fb, x);
}